// Round 7
// baseline (234.098 us; speedup 1.0000x reference)
//
#include <hip/hip_runtime.h>

#define DIM   128
#define DMASK 127
#define PLANE (DIM * DIM)     // 16384
#define VOX   (1 << 21)       // 128^3
#define NCH   12

typedef __attribute__((ext_vector_type(2))) _Float16 half2v;

// Per-channel shift pairs (d,h,w) = 2*(one_hot_idx - 1); verified (absmax 0).
__constant__ int c_sd1[12] = { 0, 0, 0, 0, 0, 2, 2, 2, 0, 0, 0, 0};
__constant__ int c_sh1[12] = { 0,-2,-2, 0, 0, 0, 0, 0, 2, 2, 2, 2};
__constant__ int c_sw1[12] = {-2, 0, 0, 2, 2, 0, 0, 0, 0, 0, 0, 0};
__constant__ int c_sd2[12] = {-2,-2, 0,-2, 0, 0, 0, 0,-2, 0, 0, 2};
__constant__ int c_sh2[12] = { 0, 0, 0, 0,-2, 0,-2, 0, 0, 0, 0, 0};
__constant__ int c_sw2[12] = { 0, 0,-2, 0, 0,-2, 0, 2, 0,-2, 2, 0};

__device__ __forceinline__ int clamp7(int v) { return min(max(v, 0), DMASK); }

// DPP wave-shift cross-lane: VALU-pipe, no DS unit. old-operand doubles as
// the boundary fix (bound_ctrl=false -> invalid source lane keeps old).
// WAVE_SHR1 (0x138): lane i <- lane i-1 (shfl_up 1).  lane0 -> old.
// WAVE_SHL1 (0x130): lane i <- lane i+1 (shfl_down 1). lane63 -> old.
__device__ __forceinline__ float dpp_shr1(float old_, float src) {
    return __int_as_float(__builtin_amdgcn_update_dpp(
        __float_as_int(old_), __float_as_int(src), 0x138, 0xF, 0xF, false));
}
__device__ __forceinline__ float dpp_shl1(float old_, float src) {
    return __int_as_float(__builtin_amdgcn_update_dpp(
        __float_as_int(old_), __float_as_int(src), 0x130, 0xF, 0xF, false));
}

// FFUSE v2 (r7): fused pipeline, DPP cross-lane, 2 blocks/CU.
// r6 ledger: fusion killed the 288MB S round-trip (WRITE 96MB -> 8B) but
// ffuse=86us profiled / ~135us timed. T1: 64 shfl(DS)/wave/plane x 12 waves
// serialize on the per-CU DS unit (~35us) -> replace with DPP wave shifts
// (VALU pipe, boundary fix absorbed by old operand). T2: 1 block/CU exposes
// cold-HBM latency at every barrier -> 8-plane d-segs, 512 blocks = 2/CU
// (VGPR 80 -> 6 waves/SIMD = 24 waves; LDS 2x48.5KB fits 160KB).
// Reducer quad rotates (it-4)%3 to round-robin the reduce cost.

#define STREAM_PIPE(IMC, WIN, HIST, IMGI, S5C)                               \
    {                                                                        \
        float tX[8], tY[8];                                                  \
        _Pragma("unroll")                                                    \
        for (int r = 0; r < 8; ++r) {                                        \
            float2 a = *(const float2*)(IMC + (pOffA + rowOffA[r] + colA));  \
            float2 b = *(const float2*)(IMC + (pOffB + rowOffB[r] + colB));  \
            a.y = fixAlo ? a.x : a.y;  a.x = fixAhi ? a.y : a.x;             \
            b.y = fixBlo ? b.x : b.y;  b.x = fixBhi ? b.y : b.x;             \
            float dx = a.x - b.x; dx *= dx;      /* D2[2l]   */              \
            float dy = a.y - b.y; dy *= dy;      /* D2[2l+1] */              \
            float lx = dpp_shr1(dx, dx);         /* D2[2l-2]; l0->dx */      \
            float ly = dpp_shr1(dx, dy);         /* D2[2l-1]; l0->dx */      \
            float rx = dpp_shl1(dy, dx);         /* D2[2l+2]; l63->dy */     \
            float ry = dpp_shl1(dy, dy);         /* D2[2l+3]; l63->dy */     \
            float m = ly + dx + dy + rx;                                     \
            tX[r] = lx + m;                      /* W-box(2l)   */           \
            tY[r] = m + ry;                      /* W-box(2l+1) */           \
        }                                                                    \
        float sx = tX[0] + tX[1] + tX[2] + tX[3] + tX[4];                    \
        float sy = tY[0] + tY[1] + tY[2] + tY[3] + tY[4];                    \
        _Pragma("unroll")                                                    \
        for (int k = 0; k < 4; ++k) {                                        \
            half2v hv = { (_Float16)sx, (_Float16)sy }; /* round first */    \
            half2v old = HIST[S5C][k];                                       \
            WIN[k].x += (float)hv[0] - (float)old[0];                        \
            WIN[k].y += (float)hv[1] - (float)old[1];                        \
            HIST[S5C][k] = hv;                                               \
            if (dowrite) {                                                   \
                half2v ov = { (_Float16)WIN[k].x, (_Float16)WIN[k].y };      \
                sb[bb][ch][IMGI][k][l] = ov;                                 \
            }                                                                \
            if (k < 3) {                                                     \
                sx += tX[k + 5] - tX[k];                                     \
                sy += tY[k + 5] - tY[k];                                     \
            }                                                                \
        }                                                                    \
    }

// One full plane iteration (both streams + optional barrier/reduce).
#define PLANE_ITER(IT_EXPR, S5C)                                             \
    {                                                                        \
        int it = (IT_EXPR);                                                  \
        int dp = clamp7(d0 - 2 + it);                                        \
        int pOffA = clamp7(dp + sd1) * (PLANE * 4);                          \
        int pOffB = clamp7(dp + sd2) * (PLANE * 4);                          \
        bool dowrite = (it >= 4);                                            \
        int bb = it & 1;                                                     \
        STREAM_PIPE(im0, win0, hist0, 0, S5C)                                \
        STREAM_PIPE(im1, win1, hist1, 1, S5C)                                \
        if (dowrite) {                                                       \
            __syncthreads();                                                 \
            if ((wv >> 2) == ((it - 4) % 3)) {                               \
                int rrow = wv & 3;                                           \
                float mn0x = 3.4e38f, mn0y = 3.4e38f, sm0x = 0.f, sm0y = 0.f;\
                float mn1x = 3.4e38f, mn1y = 3.4e38f, sm1x = 0.f, sm1y = 0.f;\
                _Pragma("unroll")                                            \
                for (int c = 0; c < 12; ++c) {                               \
                    half2v g0 = sb[bb][c][0][rrow][l];                       \
                    half2v g1 = sb[bb][c][1][rrow][l];                       \
                    float v0x = (float)g0[0], v0y = (float)g0[1];            \
                    float v1x = (float)g1[0], v1y = (float)g1[1];            \
                    mn0x = fminf(mn0x, v0x); sm0x += v0x;                    \
                    mn0y = fminf(mn0y, v0y); sm0y += v0y;                    \
                    mn1x = fminf(mn1x, v1x); sm1x += v1x;                    \
                    mn1y = fminf(mn1y, v1y); sm1y += v1y;                    \
                }                                                            \
                float i0x = __fdividef(1.0f, sm0x * (1.0f/12.0f) - mn0x);    \
                float i0y = __fdividef(1.0f, sm0y * (1.0f/12.0f) - mn0y);    \
                float i1x = __fdividef(1.0f, sm1x * (1.0f/12.0f) - mn1x);    \
                float i1y = __fdividef(1.0f, sm1y * (1.0f/12.0f) - mn1y);    \
                _Pragma("unroll")                                            \
                for (int c = 0; c < 12; ++c) {                               \
                    half2v g0 = sb[bb][c][0][rrow][l];                       \
                    half2v g1 = sb[bb][c][1][rrow][l];                       \
                    float e0x = __expf(-((float)g0[0] - mn0x) * i0x);        \
                    float e1x = __expf(-((float)g1[0] - mn1x) * i1x);        \
                    float e0y = __expf(-((float)g0[1] - mn0y) * i0y);        \
                    float e1y = __expf(-((float)g1[1] - mn1y) * i1y);        \
                    float dfx = e0x - e1x, dfy = e0y - e1y;                  \
                    acc += dfx * dfx + dfy * dfy;                            \
                }                                                            \
            }                                                                \
        }                                                                    \
    }

__global__ __launch_bounds__(768, 6) void ffuse(const float* __restrict__ img0,
                                                const float* __restrict__ img1,
                                                float* __restrict__ partial) {
    // [buf][ch][img][row][colpair] f16x2 = 48 KB static LDS
    __shared__ half2v sb[2][NCH][2][4][64];
    __shared__ float sred[12];

    int tid = threadIdx.x;
    int wv  = tid >> 6;              // 0..11 = channel
    int l   = tid & 63;

    // hs fastest: 32 consecutive blocks share the same d-window (L2-friendly)
    // hs: 32 slices of 4 rows; ds: 16 segs of 8 planes.
    int bx = blockIdx.x;
    int h0 = (bx & 31) << 2;
    int d0 = (bx >> 5) << 3;

    int ch = wv;
    int sd1 = c_sd1[ch], sh1 = c_sh1[ch], sw1 = c_sw1[ch];
    int sd2 = c_sd2[ch], sh2 = c_sh2[ch], sw2 = c_sw2[ch];

    // wave-uniform row byte-offsets (double clamp composed), 8 rows
    int rowOffA[8], rowOffB[8];
#pragma unroll
    for (int r = 0; r < 8; ++r) {
        int hq = clamp7(h0 - 2 + r);
        rowOffA[r] = clamp7(hq + sh1) * (DIM * 4);
        rowOffB[r] = clamp7(hq + sh2) * (DIM * 4);
    }

    // per-lane column byte bases (float2 at cols 2l+sw, clamped to [0,126])
    int c2 = l << 1;
    int colA = min(max(c2 + sw1, 0), 126) * 4;
    int colB = min(max(c2 + sw2, 0), 126) * 4;
    bool fixAlo = (sw1 < 0) && (l == 0);
    bool fixAhi = (sw1 > 0) && (l == 63);
    bool fixBlo = (sw2 < 0) && (l == 0);
    bool fixBhi = (sw2 > 0) && (l == 63);

    float2 win0[4], win1[4];
    half2v hist0[5][4], hist1[5][4];
#pragma unroll
    for (int k = 0; k < 4; ++k) {
        win0[k].x = 0.0f; win0[k].y = 0.0f;
        win1[k].x = 0.0f; win1[k].y = 0.0f;
#pragma unroll
        for (int s = 0; s < 5; ++s) {
            hist0[s][k] = half2v{(_Float16)0.0f, (_Float16)0.0f};
            hist1[s][k] = half2v{(_Float16)0.0f, (_Float16)0.0f};
        }
    }

    const char* im0 = (const char*)img0;
    const char* im1 = (const char*)img1;

    float acc = 0.0f;

    // 12 planes per task: 2 prologue (s5=0,1) + 2 x 5 ring (2,3,4,0,1).
#pragma unroll
    for (int j = 0; j < 2; ++j)
        PLANE_ITER(j, j)

    for (int oo = 0; oo < 2; ++oo) {
#pragma unroll
        for (int j = 0; j < 5; ++j)
            PLANE_ITER(2 + oo * 5 + j, ((2 + j) % 5))
    }

    // block reduction: every wave may hold acc (rotating reducers)
#pragma unroll
    for (int off = 32; off > 0; off >>= 1)
        acc += __shfl_down(acc, off, 64);
    if (l == 0) sred[wv] = acc;
    __syncthreads();
    if (tid == 0) {
        float s = 0.0f;
#pragma unroll
        for (int w = 0; w < 12; ++w) s += sred[w];
        partial[blockIdx.x] = s;
    }
}

// kred: sum 512 partials, write the final scalar.
__global__ __launch_bounds__(256) void kred(const float* __restrict__ partial,
                                            float* __restrict__ out) {
    int tid = threadIdx.x;
    float acc = partial[tid] + partial[tid + 256];
#pragma unroll
    for (int off = 32; off > 0; off >>= 1)
        acc += __shfl_down(acc, off, 64);
    __shared__ float smem[4];
    int lane = tid & 63, wv = tid >> 6;
    if (lane == 0) smem[wv] = acc;
    __syncthreads();
    if (tid == 0)
        out[0] = (smem[0] + smem[1] + smem[2] + smem[3])
               * (1.0f / (12.0f * (float)VOX));
}

__global__ void kdiag(float* out, float ws_mb) { out[0] = ws_mb; }

extern "C" void kernel_launch(void* const* d_in, const int* in_sizes, int n_in,
                              void* d_out, int out_size, void* d_ws, size_t ws_size,
                              hipStream_t stream) {
    const float* y_true = (const float*)d_in[0];
    const float* y_pred = (const float*)d_in[1];
    float* out = (float*)d_out;

    const size_t NEED = 4096;
    if (ws_size < NEED) {
        kdiag<<<1, 1, 0, stream>>>(out, (float)(ws_size >> 20));
        return;
    }

    float* partial = (float*)d_ws;   // 512 floats

    // 512 blocks (32 hslices x 16 dsegs), 768 threads = 12 waves (1 ch each)
    ffuse<<<dim3(512), 768, 0, stream>>>(y_true, y_pred, partial);
    kred<<<1, 256, 0, stream>>>(partial, out);
}

// Round 8
// 134.504 us; speedup vs baseline: 1.7404x; 1.7404x over previous
//
#include <hip/hip_runtime.h>

#define DIM   128
#define DMASK 127
#define PLANE (DIM * DIM)     // 16384
#define VOX   (1 << 21)       // 128^3
#define NCH   12

typedef __attribute__((ext_vector_type(2))) _Float16 half2v;

// Per-channel shift pairs (d,h,w) = 2*(one_hot_idx - 1); verified (absmax 0).
__constant__ int c_sd1[12] = { 0, 0, 0, 0, 0, 2, 2, 2, 0, 0, 0, 0};
__constant__ int c_sh1[12] = { 0,-2,-2, 0, 0, 0, 0, 0, 2, 2, 2, 2};
__constant__ int c_sw1[12] = {-2, 0, 0, 2, 2, 0, 0, 0, 0, 0, 0, 0};
__constant__ int c_sd2[12] = {-2,-2, 0,-2, 0, 0, 0, 0,-2, 0, 0, 2};
__constant__ int c_sh2[12] = { 0, 0, 0, 0,-2, 0,-2, 0, 0, 0, 0, 0};
__constant__ int c_sw2[12] = { 0, 0,-2, 0, 0,-2, 0, 2, 0,-2, 2, 0};

__device__ __forceinline__ int clamp7(int v) { return min(max(v, 0), DMASK); }

// DPP wave-shift cross-lane: VALU-pipe, no DS unit. old-operand doubles as
// the boundary fix (bound_ctrl=false -> invalid source lane keeps old).
// WAVE_SHR1 (0x138): lane i <- lane i-1 (shfl_up 1).  lane0 -> old.
// WAVE_SHL1 (0x130): lane i <- lane i+1 (shfl_down 1). lane63 -> old.
// Correctness HW-validated in r7 (absmax 0.0).
__device__ __forceinline__ float dpp_shr1(float old_, float src) {
    return __int_as_float(__builtin_amdgcn_update_dpp(
        __float_as_int(old_), __float_as_int(src), 0x138, 0xF, 0xF, false));
}
__device__ __forceinline__ float dpp_shl1(float old_, float src) {
    return __int_as_float(__builtin_amdgcn_update_dpp(
        __float_as_int(old_), __float_as_int(src), 0x130, 0xF, 0xF, false));
}

// FFUSE v3 (r8): r6 validated structure + DPP cross-lane + rotating reducers.
// LEDGER (hard rules):
//  - NEVER pass a min-waves arg to __launch_bounds__ here. r1 (256,4)->64
//    VGPR spill; r7 (768,6)->40 VGPR spill (FETCH 287MB, WRITE 255MB,
//    198us). Natural allocation (~80 VGPR) was spill-free every round.
//  - Fusion is right: r6 killed the 288MB S round-trip (WRITE 96MB -> 8B).
//  - T1 (this round): r6's 64 shfl/wave/plane-iter = ds_bpermute on the ONE
//    DS unit/CU shared by 12 waves (~4600 DS-cy vs ~1900 VALU-cy per iter)
//    -> DPP moves cross-lane to the VALU pipe (4 SIMDs), deletes cndmasks.
// Structure: 256 blocks (1/CU) x 768 threads (12 waves). Block owns a
// (4-row h-slice x 16-plane d-seg) tile; wave w = channel w, both images.
// Per output plane: f16 SSD slices -> double-buffered 48KB LDS; one
// barrier; reducer quad rotates (it-4)%3 so each wave reduces every 3rd
// plane (load balance vs r6's fixed waves 0-3).

#define STREAM_PIPE(IMC, WIN, HIST, IMGI, S5C)                               \
    {                                                                        \
        float tX[8], tY[8];                                                  \
        _Pragma("unroll")                                                    \
        for (int r = 0; r < 8; ++r) {                                        \
            float2 a = *(const float2*)(IMC + (pOffA + rowOffA[r] + colA));  \
            float2 b = *(const float2*)(IMC + (pOffB + rowOffB[r] + colB));  \
            a.y = fixAlo ? a.x : a.y;  a.x = fixAhi ? a.y : a.x;             \
            b.y = fixBlo ? b.x : b.y;  b.x = fixBhi ? b.y : b.x;             \
            float dx = a.x - b.x; dx *= dx;      /* D2[2l]   */              \
            float dy = a.y - b.y; dy *= dy;      /* D2[2l+1] */              \
            float lx = dpp_shr1(dx, dx);         /* D2[2l-2]; l0->dx */      \
            float ly = dpp_shr1(dx, dy);         /* D2[2l-1]; l0->dx */      \
            float rx = dpp_shl1(dy, dx);         /* D2[2l+2]; l63->dy */     \
            float ry = dpp_shl1(dy, dy);         /* D2[2l+3]; l63->dy */     \
            float m = ly + dx + dy + rx;                                     \
            tX[r] = lx + m;                      /* W-box(2l)   */           \
            tY[r] = m + ry;                      /* W-box(2l+1) */           \
        }                                                                    \
        float sx = tX[0] + tX[1] + tX[2] + tX[3] + tX[4];                    \
        float sy = tY[0] + tY[1] + tY[2] + tY[3] + tY[4];                    \
        _Pragma("unroll")                                                    \
        for (int k = 0; k < 4; ++k) {                                        \
            half2v hv = { (_Float16)sx, (_Float16)sy }; /* round first */    \
            half2v old = HIST[S5C][k];                                       \
            WIN[k].x += (float)hv[0] - (float)old[0];                        \
            WIN[k].y += (float)hv[1] - (float)old[1];                        \
            HIST[S5C][k] = hv;                                               \
            if (dowrite) {                                                   \
                half2v ov = { (_Float16)WIN[k].x, (_Float16)WIN[k].y };      \
                sb[bb][ch][IMGI][k][l] = ov;                                 \
            }                                                                \
            if (k < 3) {                                                     \
                sx += tX[k + 5] - tX[k];                                     \
                sy += tY[k + 5] - tY[k];                                     \
            }                                                                \
        }                                                                    \
    }

__global__ __launch_bounds__(768) void ffuse(const float* __restrict__ img0,
                                             const float* __restrict__ img1,
                                             float* __restrict__ partial) {
    // [buf][ch][img][row][colpair] f16x2 = 48 KB static LDS
    __shared__ half2v sb[2][NCH][2][4][64];
    __shared__ float sred[12];

    int tid = threadIdx.x;
    int wv  = tid >> 6;              // 0..11 = channel
    int l   = tid & 63;

    // hs fastest: 32 consecutive blocks share the same d-window (L2-friendly)
    // hs: 32 slices of 4 rows; ds: 8 segs of 16 planes.
    int bx = blockIdx.x;
    int h0 = (bx & 31) << 2;
    int d0 = (bx >> 5) << 4;

    int ch = wv;
    int sd1 = c_sd1[ch], sh1 = c_sh1[ch], sw1 = c_sw1[ch];
    int sd2 = c_sd2[ch], sh2 = c_sh2[ch], sw2 = c_sw2[ch];

    // wave-uniform row byte-offsets (double clamp composed), 8 rows
    int rowOffA[8], rowOffB[8];
#pragma unroll
    for (int r = 0; r < 8; ++r) {
        int hq = clamp7(h0 - 2 + r);
        rowOffA[r] = clamp7(hq + sh1) * (DIM * 4);
        rowOffB[r] = clamp7(hq + sh2) * (DIM * 4);
    }

    // per-lane column byte bases (float2 at cols 2l+sw, clamped to [0,126])
    int c2 = l << 1;
    int colA = min(max(c2 + sw1, 0), 126) * 4;
    int colB = min(max(c2 + sw2, 0), 126) * 4;
    bool fixAlo = (sw1 < 0) && (l == 0);
    bool fixAhi = (sw1 > 0) && (l == 63);
    bool fixBlo = (sw2 < 0) && (l == 0);
    bool fixBhi = (sw2 > 0) && (l == 63);

    float2 win0[4], win1[4];
    half2v hist0[5][4], hist1[5][4];
#pragma unroll
    for (int k = 0; k < 4; ++k) {
        win0[k].x = 0.0f; win0[k].y = 0.0f;
        win1[k].x = 0.0f; win1[k].y = 0.0f;
#pragma unroll
        for (int s = 0; s < 5; ++s) {
            hist0[s][k] = half2v{(_Float16)0.0f, (_Float16)0.0f};
            hist1[s][k] = half2v{(_Float16)0.0f, (_Float16)0.0f};
        }
    }

    const char* im0 = (const char*)img0;
    const char* im1 = (const char*)img1;

    float acc = 0.0f;

    for (int oo = 0; oo < 4; ++oo) {
#pragma unroll
        for (int s5 = 0; s5 < 5; ++s5) {
            int it = oo * 5 + s5;
            int dp = clamp7(d0 - 2 + it);
            int pOffA = clamp7(dp + sd1) * (PLANE * 4);
            int pOffB = clamp7(dp + sd2) * (PLANE * 4);
            bool dowrite = (it >= 4);
            int bb = it & 1;

            STREAM_PIPE(im0, win0, hist0, 0, s5)
            STREAM_PIPE(im1, win1, hist1, 1, s5)

            if (dowrite) {
                __syncthreads();
                if ((wv >> 2) == ((it - 4) % 3)) {
                    int rrow = wv & 3;   // 0..3
                    float mn0x = 3.4e38f, mn0y = 3.4e38f, sm0x = 0.f, sm0y = 0.f;
                    float mn1x = 3.4e38f, mn1y = 3.4e38f, sm1x = 0.f, sm1y = 0.f;
#pragma unroll
                    for (int c = 0; c < 12; ++c) {
                        half2v g0 = sb[bb][c][0][rrow][l];
                        half2v g1 = sb[bb][c][1][rrow][l];
                        float v0x = (float)g0[0], v0y = (float)g0[1];
                        float v1x = (float)g1[0], v1y = (float)g1[1];
                        mn0x = fminf(mn0x, v0x); sm0x += v0x;
                        mn0y = fminf(mn0y, v0y); sm0y += v0y;
                        mn1x = fminf(mn1x, v1x); sm1x += v1x;
                        mn1y = fminf(mn1y, v1y); sm1y += v1y;
                    }
                    float i0x = __fdividef(1.0f, sm0x * (1.0f / 12.0f) - mn0x);
                    float i0y = __fdividef(1.0f, sm0y * (1.0f / 12.0f) - mn0y);
                    float i1x = __fdividef(1.0f, sm1x * (1.0f / 12.0f) - mn1x);
                    float i1y = __fdividef(1.0f, sm1y * (1.0f / 12.0f) - mn1y);
#pragma unroll
                    for (int c = 0; c < 12; ++c) {
                        half2v g0 = sb[bb][c][0][rrow][l];
                        half2v g1 = sb[bb][c][1][rrow][l];
                        float e0x = __expf(-((float)g0[0] - mn0x) * i0x);
                        float e1x = __expf(-((float)g1[0] - mn1x) * i1x);
                        float e0y = __expf(-((float)g0[1] - mn0y) * i0y);
                        float e1y = __expf(-((float)g1[1] - mn1y) * i1y);
                        float dfx = e0x - e1x, dfy = e0y - e1y;
                        acc += dfx * dfx + dfy * dfy;
                    }
                }
            }
        }
    }

    // block reduction: every wave may hold acc (rotating reducers)
#pragma unroll
    for (int off = 32; off > 0; off >>= 1)
        acc += __shfl_down(acc, off, 64);
    if (l == 0) sred[wv] = acc;
    __syncthreads();
    if (tid == 0) {
        float s = 0.0f;
#pragma unroll
        for (int w = 0; w < 12; ++w) s += sred[w];
        partial[blockIdx.x] = s;
    }
}

// kred: sum 256 partials, write the final scalar.
__global__ __launch_bounds__(256) void kred(const float* __restrict__ partial,
                                            float* __restrict__ out) {
    int tid = threadIdx.x;
    float acc = partial[tid];
#pragma unroll
    for (int off = 32; off > 0; off >>= 1)
        acc += __shfl_down(acc, off, 64);
    __shared__ float smem[4];
    int lane = tid & 63, wv = tid >> 6;
    if (lane == 0) smem[wv] = acc;
    __syncthreads();
    if (tid == 0)
        out[0] = (smem[0] + smem[1] + smem[2] + smem[3])
               * (1.0f / (12.0f * (float)VOX));
}

__global__ void kdiag(float* out, float ws_mb) { out[0] = ws_mb; }

extern "C" void kernel_launch(void* const* d_in, const int* in_sizes, int n_in,
                              void* d_out, int out_size, void* d_ws, size_t ws_size,
                              hipStream_t stream) {
    const float* y_true = (const float*)d_in[0];
    const float* y_pred = (const float*)d_in[1];
    float* out = (float*)d_out;

    const size_t NEED = 4096;
    if (ws_size < NEED) {
        kdiag<<<1, 1, 0, stream>>>(out, (float)(ws_size >> 20));
        return;
    }

    float* partial = (float*)d_ws;   // 256 floats

    // 256 blocks (32 hslices x 8 dsegs), 768 threads = 12 waves (1 ch each)
    ffuse<<<dim3(256), 768, 0, stream>>>(y_true, y_pred, partial);
    kred<<<1, 256, 0, stream>>>(partial, out);
}